// Round 5
// baseline (722.745 us; speedup 1.0000x reference)
//
#include <hip/hip_runtime.h>
#include <hip/hip_bf16.h>

typedef unsigned short u16;
typedef unsigned int   u32;

__device__ __forceinline__ float sigmoidf_(float x){
    return 1.0f / (1.0f + __expf(-x));
}
__device__ __forceinline__ float tanhf_(float x){
    float e = __expf(2.0f * x);
    return 1.0f - 2.0f / (e + 1.0f);
}

// LDS: 65,024 B total (<= 65,536). Whh (f32, live during recurrence) is
// time-multiplexed with the tail weights; u[] with line/pp.
struct __align__(16) SharedMem {
    union {
        float whh[192 * 68];   // 52224 B — live during recurrence only
        struct {               // 9476 B — staged after recurrence
            float wl[1152];
            float bl[16];
            float wcf[640];
            float bcf[20];
            float wcc[80];
            float bcc[20];
            float wcm[400];
            float bcm[20];
            float wfin[20];
            float bfin;
        } tw;
    };
    float h[4][8 * 68];        // 8704 B — per-wave h state, row stride 68
    union {
        float u[4][32];        // recurrence only
        struct {
            float line[4][128];   // tail; reused for Phase-C partials
            float pp[4][128];
        } tl;
    };
};

__global__ __launch_bounds__(256, 2)
void FRAPRQ_fused_kernel(
    const float* __restrict__ feat,       // (B,16) f32
    const float* __restrict__ hist,       // (B,64,24) f32
    const int*   __restrict__ relation,   // (8,7) i32
    const float* __restrict__ emb_phase,  // (2,4)
    const float* __restrict__ Wv,         // (4,1)
    const float* __restrict__ bv,         // (4)
    const float* __restrict__ Wh,         // (4,3)
    const float* __restrict__ bh,         // (4)
    const float* __restrict__ Wih,        // (192,4)
    const float* __restrict__ Whh,        // (192,64)
    const float* __restrict__ bih,        // (192)
    const float* __restrict__ bhh,        // (192)
    const float* __restrict__ Wl,         // (16,72)
    const float* __restrict__ bl,         // (16)
    const float* __restrict__ emb_const,  // (2,4)
    const float* __restrict__ Wcf,        // (20,32)
    const float* __restrict__ bcf,        // (20)
    const float* __restrict__ Wcc,        // (20,4)
    const float* __restrict__ bcc,        // (20)
    const float* __restrict__ Wcm,        // (20,20)
    const float* __restrict__ bcm,        // (20)
    const float* __restrict__ Wfin,       // (1,20)
    const float* __restrict__ bfin,       // (1)
    float* __restrict__ out)              // (B,8) f32
{
    __shared__ SharedMem sm;
    const int tid = threadIdx.x;

    // ---- stage Whh to LDS (row stride 68 -> conflict-benign b128 reads) ----
    for (int i = tid; i < 192 * 64; i += 256){
        int r = i >> 6, k = i & 63;
        sm.whh[r * 68 + k] = Whh[i];
    }

    const int wave = tid >> 6;
    const int lane = tid & 63;
    const int b = blockIdx.x * 4 + wave;

    // ---- per-lane GRU weights (lane j = hidden unit) ----
    float wir[4], wiz[4], win_[4];
    #pragma unroll
    for (int c = 0; c < 4; ++c){
        wir[c]  = Wih[(      lane) * 4 + c];
        wiz[c]  = Wih[( 64 + lane) * 4 + c];
        win_[c] = Wih[(128 + lane) * 4 + c];
    }
    const float bc_r = bih[lane]       + bhh[lane];
    const float bc_z = bih[64 + lane]  + bhh[64 + lane];
    const float bi_n = bih[128 + lane];
    const float bh_n = bhh[128 + lane];

    // u-computation: lanes 0..31 produce u[s][c] (s = lane>>2, c = lane&3)
    const int s_u = (lane >> 2) & 7;
    const int c_u = lane & 3;
    const float wh0 = Wh[c_u * 3 + 0];
    const float wh1 = Wh[c_u * 3 + 1];
    const float wh2 = Wh[c_u * 3 + 2];
    const float bhc = bh[c_u];

    float h_reg[8];
    #pragma unroll
    for (int s = 0; s < 8; ++s){ h_reg[s] = 0.0f; sm.h[wave][s * 68 + lane] = 0.0f; }

    // scalar f32 history loads with software prefetch
    const float* __restrict__ hrow = hist + (size_t)b * (64 * 24);
    float x0 = hrow[s_u];
    float x1 = hrow[s_u + 8];
    float x2 = hrow[s_u + 16];

    __syncthreads();  // staging + h init visible

    for (int t = 0; t < 64; ++t){
        const int tn = (t + 1 < 64) ? (t + 1) : 63;
        const float p0 = hrow[tn * 24 + s_u];
        const float p1 = hrow[tn * 24 + s_u + 8];
        const float p2 = hrow[tn * 24 + s_u + 16];

        if (lane < 32)
            sm.u[wave][lane] = sigmoidf_(wh0 * x0 + wh1 * x1 + wh2 * x2 + bhc);
        __syncthreads();  // u(t) visible

        float ar[8], az[8], ain[8], ahn[8];
        #pragma unroll
        for (int s = 0; s < 8; ++s){ ar[s] = bc_r; az[s] = bc_z; ain[s] = bi_n; ahn[s] = bh_n; }

        // input-gate contribution (u broadcast from LDS)
        #pragma unroll
        for (int s = 0; s < 8; ++s){
            const float4 u4 = *reinterpret_cast<const float4*>(&sm.u[wave][s * 4]);
            ar[s]  += wir[0]*u4.x  + wir[1]*u4.y  + wir[2]*u4.z  + wir[3]*u4.w;
            az[s]  += wiz[0]*u4.x  + wiz[1]*u4.y  + wiz[2]*u4.z  + wiz[3]*u4.w;
            ain[s] += win_[0]*u4.x + win_[1]*u4.y + win_[2]*u4.z + win_[3]*u4.w;
        }

        // recurrent matmul: each Whh b128 read amortized over 8 sequences
        #pragma unroll 4
        for (int kc = 0; kc < 64; kc += 4){
            const float4 wr = *reinterpret_cast<const float4*>(&sm.whh[(      lane) * 68 + kc]);
            const float4 wz = *reinterpret_cast<const float4*>(&sm.whh[( 64 + lane) * 68 + kc]);
            const float4 wn = *reinterpret_cast<const float4*>(&sm.whh[(128 + lane) * 68 + kc]);
            #pragma unroll
            for (int s = 0; s < 8; ++s){
                const float4 h4 = *reinterpret_cast<const float4*>(&sm.h[wave][s * 68 + kc]);
                ar[s]  += wr.x*h4.x + wr.y*h4.y + wr.z*h4.z + wr.w*h4.w;
                az[s]  += wz.x*h4.x + wz.y*h4.y + wz.z*h4.z + wz.w*h4.w;
                ahn[s] += wn.x*h4.x + wn.y*h4.y + wn.z*h4.z + wn.w*h4.w;
            }
        }

        // gates + state update
        #pragma unroll
        for (int s = 0; s < 8; ++s){
            const float r = sigmoidf_(ar[s]);
            const float z = sigmoidf_(az[s]);
            const float cand = tanhf_(ain[s] + r * ahn[s]);
            h_reg[s] = (1.0f - z) * cand + z * h_reg[s];
        }
        #pragma unroll
        for (int s = 0; s < 8; ++s) sm.h[wave][s * 68 + lane] = h_reg[s];

        x0 = p0; x1 = p1; x2 = p2;
    }
    __syncthreads();  // recurrence done; whh region is now dead

    // ---- stage tail weights into the (dead) whh region ----
    for (int i = tid; i < 1152; i += 256) sm.tw.wl[i]  = Wl[i];
    for (int i = tid; i <  640; i += 256) sm.tw.wcf[i] = Wcf[i];
    for (int i = tid; i <  400; i += 256) sm.tw.wcm[i] = Wcm[i];
    if (tid < 80) sm.tw.wcc[tid] = Wcc[tid];
    if (tid < 20){
        sm.tw.bcf[tid]  = bcf[tid];
        sm.tw.bcc[tid]  = bcc[tid];
        sm.tw.bcm[tid]  = bcm[tid];
        sm.tw.wfin[tid] = Wfin[tid];
    }
    if (tid < 16) sm.tw.bl[tid] = bl[tid];
    if (tid == 0) sm.tw.bfin = bfin[0];
    __syncthreads();

    // ---- tail: per-wave (one b), 64 lanes ----
    // Phase A: line[l][o] = relu(lane_feat . Wl[o]); lane -> (l = lane>>3, o & o+8)
    {
        const int l = lane >> 3, o = lane & 7;
        float fv[8];
        const float vraw = feat[b * 16 + 8 + l];
        const int   bit  = ((int)feat[b * 16 + l]) & 1;   // values are exact 0.0/1.0
        #pragma unroll
        for (int c = 0; c < 4; ++c){
            fv[c]     = sigmoidf_(vraw * Wv[c] + bv[c]);
            fv[4 + c] = sigmoidf_(emb_phase[bit * 4 + c]);
        }
        #pragma unroll
        for (int half = 0; half < 2; ++half){
            const int oo = o + half * 8;
            float acc = sm.tw.bl[oo];
            #pragma unroll
            for (int f = 0; f < 8; ++f) acc += fv[f] * sm.tw.wl[oo * 72 + f];
            for (int k = 0; k < 64; ++k) acc += sm.h[wave][l * 68 + k] * sm.tw.wl[oo * 72 + 8 + k];
            sm.tl.line[wave][l * 16 + oo] = fmaxf(acc, 0.0f);
        }
    }
    __syncthreads();
    // Phase B: pp[p][o] = line[PL0[p]][o] + line[PL1[p]][o]
    {
        const int p = lane >> 3, o = lane & 7;
        const int l0 = (0x64204501u >> (p * 4)) & 15;
        const int l1 = (0x75316723u >> (p * 4)) & 15;
        sm.tl.pp[wave][p * 16 + o]     = sm.tl.line[wave][l0 * 16 + o]     + sm.tl.line[wave][l1 * 16 + o];
        sm.tl.pp[wave][p * 16 + o + 8] = sm.tl.line[wave][l0 * 16 + o + 8] + sm.tl.line[wave][l1 * 16 + o + 8];
    }
    __syncthreads();
    // Phase C: one lane per (p,q) pair; partials into the dead `line` region
    if (lane < 56){
        const int p  = lane / 7;
        const int qi = lane - p * 7;
        const int jl = qi + (qi >= p ? 1 : 0);
        float fmv[32];
        #pragma unroll
        for (int f = 0; f < 16; ++f){
            fmv[f]      = sm.tl.pp[wave][p  * 16 + f];
            fmv[16 + f] = sm.tl.pp[wave][jl * 16 + f];
        }
        const int rel = relation[p * 7 + qi] & 1;   // values are 0/1
        float ce[4];
        #pragma unroll
        for (int c = 0; c < 4; ++c) ce[c] = emb_const[rel * 4 + c];
        float m[20];
        for (int o = 0; o < 20; ++o){
            float xf = sm.tw.bcf[o];
            #pragma unroll
            for (int f = 0; f < 32; ++f) xf += fmv[f] * sm.tw.wcf[o * 32 + f];
            float yc = sm.tw.bcc[o];
            #pragma unroll
            for (int c = 0; c < 4; ++c) yc += ce[c] * sm.tw.wcc[o * 4 + c];
            m[o] = fmaxf(xf, 0.0f) * fmaxf(yc, 0.0f);
        }
        float fin = sm.tw.bfin;
        for (int o = 0; o < 20; ++o){
            float zz = sm.tw.bcm[o];
            #pragma unroll
            for (int c = 0; c < 20; ++c) zz += m[c] * sm.tw.wcm[o * 20 + c];
            fin += fmaxf(zz, 0.0f) * sm.tw.wfin[o];
        }
        sm.tl.line[wave][lane] = fin;   // line region is dead after Phase B
    }
    __syncthreads();
    if (lane < 8){
        float acc = 0.0f;
        #pragma unroll
        for (int q = 0; q < 7; ++q) acc += sm.tl.line[wave][lane * 7 + q];
        out[b * 8 + lane] = acc;        // f32 output, per harness contract
    }
}

extern "C" void kernel_launch(void* const* d_in, const int* in_sizes, int n_in,
                              void* d_out, int out_size, void* d_ws, size_t ws_size,
                              hipStream_t stream) {
    (void)n_in; (void)d_ws; (void)ws_size; (void)out_size;
    const float* feat      = (const float*)d_in[0];
    const float* hist      = (const float*)d_in[1];
    const int*   relation  = (const int*)d_in[2];
    const float* emb_phase = (const float*)d_in[3];
    const float* Wv        = (const float*)d_in[4];
    const float* bv        = (const float*)d_in[5];
    const float* Wh        = (const float*)d_in[6];
    const float* bh        = (const float*)d_in[7];
    const float* Wih       = (const float*)d_in[8];
    const float* Whh       = (const float*)d_in[9];
    const float* bih       = (const float*)d_in[10];
    const float* bhh       = (const float*)d_in[11];
    const float* Wl        = (const float*)d_in[12];
    const float* bl        = (const float*)d_in[13];
    const float* emb_const = (const float*)d_in[14];
    const float* Wcf       = (const float*)d_in[15];
    const float* bcf       = (const float*)d_in[16];
    const float* Wcc       = (const float*)d_in[17];
    const float* bcc       = (const float*)d_in[18];
    const float* Wcm       = (const float*)d_in[19];
    const float* bcm       = (const float*)d_in[20];
    const float* Wfin      = (const float*)d_in[21];
    const float* bfin      = (const float*)d_in[22];
    float* out = (float*)d_out;

    const int B = in_sizes[0] / 16;     // 2048
    const int nblocks = B / 4;          // 4 waves/block, 1 b per wave
    FRAPRQ_fused_kernel<<<nblocks, 256, 0, stream>>>(
        feat, hist, relation, emb_phase, Wv, bv, Wh, bh, Wih, Whh, bih, bhh,
        Wl, bl, emb_const, Wcf, bcf, Wcc, bcc, Wcm, bcm, Wfin, bfin, out);
}

// Round 6
// 483.485 us; speedup vs baseline: 1.4949x; 1.4949x over previous
//
#include <hip/hip_runtime.h>
#include <hip/hip_bf16.h>

typedef unsigned short u16;
typedef unsigned int   u32;

// v_rcp_f32-based activations: ~1e-7 rel error, 4-5 VALU inst each.
__device__ __forceinline__ float sigmoidf_(float x){
    return __builtin_amdgcn_rcpf(1.0f + __expf(-x));
}
__device__ __forceinline__ float tanhf_(float x){
    return 1.0f - 2.0f * __builtin_amdgcn_rcpf(__expf(2.0f * x) + 1.0f);
}

// LDS: 65,024 B total (<= 65,536). Whh (f32, live during recurrence) is
// time-multiplexed with the tail weights; u[] with line/pp.
struct __align__(16) SharedMem {
    union {
        float whh[192 * 68];   // 52224 B — live during recurrence only
        struct {               // 9476 B — staged after recurrence
            float wl[1152];
            float bl[16];
            float wcf[640];
            float bcf[20];
            float wcc[80];
            float bcc[20];
            float wcm[400];
            float bcm[20];
            float wfin[20];
            float bfin;
        } tw;
    };
    float h[4][8 * 68];        // 8704 B — per-wave h state, row stride 68
    union {
        float u[4][32];        // recurrence only
        struct {
            float line[4][128];   // tail; reused for Phase-C partials
            float pp[4][128];
        } tl;
    };
};

__global__ __launch_bounds__(256, 2)
void FRAPRQ_fused_kernel(
    const float* __restrict__ feat,       // (B,16) f32
    const float* __restrict__ hist,       // (B,64,24) f32
    const int*   __restrict__ relation,   // (8,7) i32
    const float* __restrict__ emb_phase,  // (2,4)
    const float* __restrict__ Wv,         // (4,1)
    const float* __restrict__ bv,         // (4)
    const float* __restrict__ Wh,         // (4,3)
    const float* __restrict__ bh,         // (4)
    const float* __restrict__ Wih,        // (192,4)
    const float* __restrict__ Whh,        // (192,64)
    const float* __restrict__ bih,        // (192)
    const float* __restrict__ bhh,        // (192)
    const float* __restrict__ Wl,         // (16,72)
    const float* __restrict__ bl,         // (16)
    const float* __restrict__ emb_const,  // (2,4)
    const float* __restrict__ Wcf,        // (20,32)
    const float* __restrict__ bcf,        // (20)
    const float* __restrict__ Wcc,        // (20,4)
    const float* __restrict__ bcc,        // (20)
    const float* __restrict__ Wcm,        // (20,20)
    const float* __restrict__ bcm,        // (20)
    const float* __restrict__ Wfin,       // (1,20)
    const float* __restrict__ bfin,       // (1)
    float* __restrict__ out)              // (B,8) f32
{
    __shared__ SharedMem sm;
    const int tid = threadIdx.x;

    // ---- stage Whh to LDS (row stride 68) ----
    for (int i = tid; i < 192 * 64; i += 256){
        int r = i >> 6, k = i & 63;
        sm.whh[r * 68 + k] = Whh[i];
    }

    const int wave = tid >> 6;
    const int lane = tid & 63;
    const int b = blockIdx.x * 4 + wave;

    // ---- per-lane GRU weights (lane j = hidden unit) ----
    float wir[4], wiz[4], win_[4];
    #pragma unroll
    for (int c = 0; c < 4; ++c){
        wir[c]  = Wih[(      lane) * 4 + c];
        wiz[c]  = Wih[( 64 + lane) * 4 + c];
        win_[c] = Wih[(128 + lane) * 4 + c];
    }
    const float bc_r = bih[lane]       + bhh[lane];
    const float bc_z = bih[64 + lane]  + bhh[64 + lane];
    const float bi_n = bih[128 + lane];
    const float bh_n = bhh[128 + lane];

    // u-computation: lanes 0..31 produce u[s][c] (s = lane>>2, c = lane&3)
    const int s_u = (lane >> 2) & 7;
    const int c_u = lane & 3;
    const float wh0 = Wh[c_u * 3 + 0];
    const float wh1 = Wh[c_u * 3 + 1];
    const float wh2 = Wh[c_u * 3 + 2];
    const float bhc = bh[c_u];

    float h_reg[8];
    #pragma unroll
    for (int s = 0; s < 8; ++s){ h_reg[s] = 0.0f; sm.h[wave][s * 68 + lane] = 0.0f; }

    // scalar f32 history loads with software prefetch
    const float* __restrict__ hrow = hist + (size_t)b * (64 * 24);
    float x0 = hrow[s_u];
    float x1 = hrow[s_u + 8];
    float x2 = hrow[s_u + 16];

    __syncthreads();  // cross-wave: whh staging visible to all waves

    // NOTE: inside the t-loop, every LDS object touched (sm.u[wave], sm.h[wave])
    // is wave-private. Intra-wave DS ops execute in order and the compiler
    // inserts lgkmcnt waits on the data dependencies — no s_barrier needed.
    for (int t = 0; t < 64; ++t){
        const int tn = (t + 1 < 64) ? (t + 1) : 63;
        const float p0 = hrow[tn * 24 + s_u];
        const float p1 = hrow[tn * 24 + s_u + 8];
        const float p2 = hrow[tn * 24 + s_u + 16];

        if (lane < 32)
            sm.u[wave][lane] = sigmoidf_(fmaf(wh0, x0, fmaf(wh1, x1, fmaf(wh2, x2, bhc))));
        __builtin_amdgcn_wave_barrier();  // pin scheduling; intra-wave dep handles the rest

        float ar[8], az[8], ain[8], ahn[8];
        #pragma unroll
        for (int s = 0; s < 8; ++s){ ar[s] = bc_r; az[s] = bc_z; ain[s] = bi_n; ahn[s] = bh_n; }

        // input-gate contribution (u broadcast from LDS, wave-private)
        #pragma unroll
        for (int s = 0; s < 8; ++s){
            const float4 u4 = *reinterpret_cast<const float4*>(&sm.u[wave][s * 4]);
            ar[s]  = fmaf(wir[0], u4.x, ar[s]);  ar[s]  = fmaf(wir[1], u4.y, ar[s]);
            ar[s]  = fmaf(wir[2], u4.z, ar[s]);  ar[s]  = fmaf(wir[3], u4.w, ar[s]);
            az[s]  = fmaf(wiz[0], u4.x, az[s]);  az[s]  = fmaf(wiz[1], u4.y, az[s]);
            az[s]  = fmaf(wiz[2], u4.z, az[s]);  az[s]  = fmaf(wiz[3], u4.w, az[s]);
            ain[s] = fmaf(win_[0], u4.x, ain[s]); ain[s] = fmaf(win_[1], u4.y, ain[s]);
            ain[s] = fmaf(win_[2], u4.z, ain[s]); ain[s] = fmaf(win_[3], u4.w, ain[s]);
        }

        // recurrent matmul: fully unrolled -> immediate-offset ds_reads
        #pragma unroll
        for (int kc = 0; kc < 64; kc += 4){
            const float4 wr = *reinterpret_cast<const float4*>(&sm.whh[(      lane) * 68 + kc]);
            const float4 wz = *reinterpret_cast<const float4*>(&sm.whh[( 64 + lane) * 68 + kc]);
            const float4 wn = *reinterpret_cast<const float4*>(&sm.whh[(128 + lane) * 68 + kc]);
            #pragma unroll
            for (int s = 0; s < 8; ++s){
                const float4 h4 = *reinterpret_cast<const float4*>(&sm.h[wave][s * 68 + kc]);
                ar[s]  = fmaf(wr.x, h4.x, ar[s]);  ar[s]  = fmaf(wr.y, h4.y, ar[s]);
                ar[s]  = fmaf(wr.z, h4.z, ar[s]);  ar[s]  = fmaf(wr.w, h4.w, ar[s]);
                az[s]  = fmaf(wz.x, h4.x, az[s]);  az[s]  = fmaf(wz.y, h4.y, az[s]);
                az[s]  = fmaf(wz.z, h4.z, az[s]);  az[s]  = fmaf(wz.w, h4.w, az[s]);
                ahn[s] = fmaf(wn.x, h4.x, ahn[s]); ahn[s] = fmaf(wn.y, h4.y, ahn[s]);
                ahn[s] = fmaf(wn.z, h4.z, ahn[s]); ahn[s] = fmaf(wn.w, h4.w, ahn[s]);
            }
        }

        // gates + state update
        #pragma unroll
        for (int s = 0; s < 8; ++s){
            const float r = sigmoidf_(ar[s]);
            const float z = sigmoidf_(az[s]);
            const float cand = tanhf_(fmaf(r, ahn[s], ain[s]));
            h_reg[s] = fmaf(z, h_reg[s] - cand, cand);   // (1-z)*cand + z*h
        }
        __builtin_amdgcn_wave_barrier();
        #pragma unroll
        for (int s = 0; s < 8; ++s) sm.h[wave][s * 68 + lane] = h_reg[s];

        x0 = p0; x1 = p1; x2 = p2;
    }
    __syncthreads();  // cross-wave: all waves done reading whh (union flips to tw)

    // ---- stage tail weights into the (dead) whh region ----
    for (int i = tid; i < 1152; i += 256) sm.tw.wl[i]  = Wl[i];
    for (int i = tid; i <  640; i += 256) sm.tw.wcf[i] = Wcf[i];
    for (int i = tid; i <  400; i += 256) sm.tw.wcm[i] = Wcm[i];
    if (tid < 80) sm.tw.wcc[tid] = Wcc[tid];
    if (tid < 20){
        sm.tw.bcf[tid]  = bcf[tid];
        sm.tw.bcc[tid]  = bcc[tid];
        sm.tw.bcm[tid]  = bcm[tid];
        sm.tw.wfin[tid] = Wfin[tid];
    }
    if (tid < 16) sm.tw.bl[tid] = bl[tid];
    if (tid == 0) sm.tw.bfin = bfin[0];
    __syncthreads();  // cross-wave: tw staging visible

    // ---- tail: per-wave (one b), all LDS below is wave-private ----
    // Phase A: line[l][o] = relu(lane_feat . Wl[o]); lane -> (l = lane>>3, o & o+8)
    {
        const int l = lane >> 3, o = lane & 7;
        float fv[8];
        const float vraw = feat[b * 16 + 8 + l];
        const int   bit  = ((int)feat[b * 16 + l]) & 1;   // values are exact 0.0/1.0
        #pragma unroll
        for (int c = 0; c < 4; ++c){
            fv[c]     = sigmoidf_(fmaf(vraw, Wv[c], bv[c]));
            fv[4 + c] = sigmoidf_(emb_phase[bit * 4 + c]);
        }
        #pragma unroll
        for (int half = 0; half < 2; ++half){
            const int oo = o + half * 8;
            float acc = sm.tw.bl[oo];
            #pragma unroll
            for (int f = 0; f < 8; ++f) acc = fmaf(fv[f], sm.tw.wl[oo * 72 + f], acc);
            for (int k = 0; k < 64; ++k) acc = fmaf(sm.h[wave][l * 68 + k], sm.tw.wl[oo * 72 + 8 + k], acc);
            sm.tl.line[wave][l * 16 + oo] = fmaxf(acc, 0.0f);
        }
    }
    __builtin_amdgcn_wave_barrier();
    // Phase B: pp[p][o] = line[PL0[p]][o] + line[PL1[p]][o]
    {
        const int p = lane >> 3, o = lane & 7;
        const int l0 = (0x64204501u >> (p * 4)) & 15;
        const int l1 = (0x75316723u >> (p * 4)) & 15;
        sm.tl.pp[wave][p * 16 + o]     = sm.tl.line[wave][l0 * 16 + o]     + sm.tl.line[wave][l1 * 16 + o];
        sm.tl.pp[wave][p * 16 + o + 8] = sm.tl.line[wave][l0 * 16 + o + 8] + sm.tl.line[wave][l1 * 16 + o + 8];
    }
    __builtin_amdgcn_wave_barrier();
    // Phase C: one lane per (p,q) pair; partials into the dead `line` region
    if (lane < 56){
        const int p  = lane / 7;
        const int qi = lane - p * 7;
        const int jl = qi + (qi >= p ? 1 : 0);
        float fmv[32];
        #pragma unroll
        for (int f = 0; f < 16; ++f){
            fmv[f]      = sm.tl.pp[wave][p  * 16 + f];
            fmv[16 + f] = sm.tl.pp[wave][jl * 16 + f];
        }
        const int rel = relation[p * 7 + qi] & 1;   // values are 0/1
        float ce[4];
        #pragma unroll
        for (int c = 0; c < 4; ++c) ce[c] = emb_const[rel * 4 + c];
        float m[20];
        for (int o = 0; o < 20; ++o){
            float xf = sm.tw.bcf[o];
            #pragma unroll
            for (int f = 0; f < 32; ++f) xf = fmaf(fmv[f], sm.tw.wcf[o * 32 + f], xf);
            float yc = sm.tw.bcc[o];
            #pragma unroll
            for (int c = 0; c < 4; ++c) yc = fmaf(ce[c], sm.tw.wcc[o * 4 + c], yc);
            m[o] = fmaxf(xf, 0.0f) * fmaxf(yc, 0.0f);
        }
        float fin = sm.tw.bfin;
        for (int o = 0; o < 20; ++o){
            float zz = sm.tw.bcm[o];
            #pragma unroll
            for (int c = 0; c < 20; ++c) zz = fmaf(m[c], sm.tw.wcm[o * 20 + c], zz);
            fin = fmaf(fmaxf(zz, 0.0f), sm.tw.wfin[o], fin);
        }
        sm.tl.line[wave][lane] = fin;   // line region is dead after Phase B
    }
    __builtin_amdgcn_wave_barrier();
    if (lane < 8){
        float acc = 0.0f;
        #pragma unroll
        for (int q = 0; q < 7; ++q) acc += sm.tl.line[wave][lane * 7 + q];
        out[b * 8 + lane] = acc;        // f32 output, per harness contract
    }
}

extern "C" void kernel_launch(void* const* d_in, const int* in_sizes, int n_in,
                              void* d_out, int out_size, void* d_ws, size_t ws_size,
                              hipStream_t stream) {
    (void)n_in; (void)d_ws; (void)ws_size; (void)out_size;
    const float* feat      = (const float*)d_in[0];
    const float* hist      = (const float*)d_in[1];
    const int*   relation  = (const int*)d_in[2];
    const float* emb_phase = (const float*)d_in[3];
    const float* Wv        = (const float*)d_in[4];
    const float* bv        = (const float*)d_in[5];
    const float* Wh        = (const float*)d_in[6];
    const float* bh        = (const float*)d_in[7];
    const float* Wih       = (const float*)d_in[8];
    const float* Whh       = (const float*)d_in[9];
    const float* bih       = (const float*)d_in[10];
    const float* bhh       = (const float*)d_in[11];
    const float* Wl        = (const float*)d_in[12];
    const float* bl        = (const float*)d_in[13];
    const float* emb_const = (const float*)d_in[14];
    const float* Wcf       = (const float*)d_in[15];
    const float* bcf       = (const float*)d_in[16];
    const float* Wcc       = (const float*)d_in[17];
    const float* bcc       = (const float*)d_in[18];
    const float* Wcm       = (const float*)d_in[19];
    const float* bcm       = (const float*)d_in[20];
    const float* Wfin      = (const float*)d_in[21];
    const float* bfin      = (const float*)d_in[22];
    float* out = (float*)d_out;

    const int B = in_sizes[0] / 16;     // 2048
    const int nblocks = B / 4;          // 4 waves/block, 1 b per wave
    FRAPRQ_fused_kernel<<<nblocks, 256, 0, stream>>>(
        feat, hist, relation, emb_phase, Wv, bv, Wh, bh, Wih, Whh, bih, bhh,
        Wl, bl, emb_const, Wcf, bcf, Wcc, bcc, Wcm, bcm, Wfin, bfin, out);
}

// Round 7
// 329.471 us; speedup vs baseline: 2.1937x; 1.4675x over previous
//
#include <hip/hip_runtime.h>

typedef unsigned short u16;
typedef unsigned int   u32;

typedef __attribute__((ext_vector_type(8))) short short8;   // 8 bf16 (4 VGPRs)
typedef __attribute__((ext_vector_type(4))) float f32x4;    // MFMA acc

union Frag { u32 u[4]; short8 s; };

__device__ __forceinline__ u32 fbits(float f){ union{float f;u32 u;}x; x.f=f; return x.u; }
__device__ __forceinline__ float bitsf(u32 u){ union{u32 u;float f;}x; x.u=u; return x.f; }
// pack two f32 -> packed bf16 pair by TRUNCATION (1 v_perm): low16 = a_hi16, high16 = b_hi16
__device__ __forceinline__ u32 pack_trunc(float a, float b){
    return __builtin_amdgcn_perm(fbits(b), fbits(a), 0x07060302u);
}
__device__ __forceinline__ u32 bf16_rne(float a){
    u32 u = fbits(a); return (u + 0x7FFFu + ((u >> 16) & 1u)) >> 16;
}
__device__ __forceinline__ u32 pack_rne(float a, float b){
    return bf16_rne(a) | (bf16_rne(b) << 16);
}
__device__ __forceinline__ float sigmoidf_(float x){
    return __builtin_amdgcn_rcpf(1.0f + __expf(-x));
}
__device__ __forceinline__ float tanhf_(float x){
    return 1.0f - 2.0f * __builtin_amdgcn_rcpf(__expf(2.0f * x) + 1.0f);
}

// LDS ~35 KB: h is per-wave [16 seqs][64 k] f32, row stride 68 (16B-aligned rows).
struct __align__(16) SharedMem {
    float wih[192 * 4];     // 3072 B, Wih rows (f32)
    float h[4][16 * 68];    // 17408 B, per-wave hidden state [s][k]
    float u[4][64];         // 1024 B, per-wave u[s*4+c]
    float wl[1152];
    float bl[16];
    float wcf[640];
    float bcf[20];
    float wcc[80];
    float bcc[20];
    float wcm[400];
    float bcm[20];
    float wfin[20];
    float bfin;
    float line[4][128];
    float pp[4][128];
};

__global__ __launch_bounds__(256, 1)
void FRAPRQ_fused_kernel(
    const float* __restrict__ feat,       // (B,16)
    const float* __restrict__ hist,       // (B,64,24)
    const int*   __restrict__ relation,   // (8,7)
    const float* __restrict__ emb_phase,  // (2,4)
    const float* __restrict__ Wv,         // (4,1)
    const float* __restrict__ bv,         // (4)
    const float* __restrict__ Wh,         // (4,3)
    const float* __restrict__ bh,         // (4)
    const float* __restrict__ Wih,        // (192,4)
    const float* __restrict__ Whh,        // (192,64)
    const float* __restrict__ bih,        // (192)
    const float* __restrict__ bhh,        // (192)
    const float* __restrict__ Wl,         // (16,72)
    const float* __restrict__ bl,         // (16)
    const float* __restrict__ emb_const,  // (2,4)
    const float* __restrict__ Wcf,        // (20,32)
    const float* __restrict__ bcf,        // (20)
    const float* __restrict__ Wcc,        // (20,4)
    const float* __restrict__ bcc,        // (20)
    const float* __restrict__ Wcm,        // (20,20)
    const float* __restrict__ bcm,        // (20)
    const float* __restrict__ Wfin,      // (1,20)
    const float* __restrict__ bfin,      // (1)
    float* __restrict__ out)             // (B,8)
{
    __shared__ SharedMem sm;
    const int tid  = threadIdx.x;
    const int wave = tid >> 6;
    const int lane = tid & 63;
    const int sq   = lane & 15;   // MFMA column: local seq s (2 b's x 8 lanes)
    const int q    = lane >> 4;   // MFMA quad
    const int b_base = (blockIdx.x * 4 + wave) * 2;

    // ---- stage shared weights (all waves cooperate, once) ----
    for (int i = tid; i <  768; i += 256) sm.wih[i] = Wih[i];
    for (int i = tid; i < 1152; i += 256) sm.wl[i]  = Wl[i];
    for (int i = tid; i <  640; i += 256) sm.wcf[i] = Wcf[i];
    for (int i = tid; i <  400; i += 256) sm.wcm[i] = Wcm[i];
    if (tid < 80) sm.wcc[tid] = Wcc[tid];
    if (tid < 20){
        sm.bcf[tid]  = bcf[tid];
        sm.bcc[tid]  = bcc[tid];
        sm.bcm[tid]  = bcm[tid];
        sm.wfin[tid] = Wfin[tid];
    }
    if (tid < 16) sm.bl[tid] = bl[tid];
    if (tid == 0) sm.bfin = bfin[0];

    float* hw = &sm.h[wave][0];
    float* uw = &sm.u[wave][0];
    for (int i = lane; i < 16 * 68; i += 64) hw[i] = 0.0f;

    // ---- A-fragments: Whh split to bf16 hi/lo, RNE, A-layout, in VGPRs ----
    // A[m=lane&15 -> row 16mt+sq][k = 32kt + 8q + j]
    Frag ahi[12][2], alo[12][2];
    #pragma unroll
    for (int mt = 0; mt < 12; ++mt){
        const int row = 16 * mt + sq;
        #pragma unroll
        for (int kt = 0; kt < 2; ++kt){
            const float* wp = Whh + row * 64 + 32 * kt + 8 * q;
            float f[8];
            #pragma unroll
            for (int i = 0; i < 8; ++i) f[i] = wp[i];
            #pragma unroll
            for (int p = 0; p < 4; ++p){
                const u32 hi = pack_rne(f[2*p], f[2*p+1]);
                ahi[mt][kt].u[p] = hi;
                const float l0 = f[2*p]   - bitsf((hi & 0xFFFFu) << 16);
                const float l1 = f[2*p+1] - bitsf(hi & 0xFFFF0000u);
                alo[mt][kt].u[p] = pack_rne(l0, l1);
            }
        }
    }

    // ---- per-lane bias constants ----
    // C/D: row = 16mt + 4q + reg, col = sq. mt 0..3 = r, 4..7 = z, 8..11 = n.
    float ginit[12][4], bhhn[4][4];
    #pragma unroll
    for (int mt = 0; mt < 12; ++mt){
        #pragma unroll
        for (int r = 0; r < 4; ++r){
            const int a = 16 * mt + 4 * q + r;
            ginit[mt][r] = bih[a] + (mt < 8 ? bhh[a] : 0.0f);
            if (mt >= 8) bhhn[mt - 8][r] = bhh[a];
        }
    }

    // ---- u path: lane computes u[s=sq][c=q] ----
    const int bs = b_base + (sq >> 3);
    const int ls = sq & 7;
    const float* hb = hist + (size_t)bs * 1536;
    const float wh0 = Wh[q*3+0], wh1 = Wh[q*3+1], wh2 = Wh[q*3+2], bhc = bh[q];
    float x0 = hb[ls], x1 = hb[ls + 8], x2 = hb[ls + 16];

    float hreg[4][4];
    #pragma unroll
    for (int m = 0; m < 4; ++m)
        #pragma unroll
        for (int r = 0; r < 4; ++r) hreg[m][r] = 0.0f;

    __syncthreads();   // staging visible to all waves

    #pragma unroll 1
    for (int t = 0; t < 64; ++t){
        const int tn = (t + 1 < 64) ? (t + 1) : 63;
        const float p0 = hb[tn*24 + ls], p1 = hb[tn*24 + ls + 8], p2 = hb[tn*24 + ls + 16];

        // u(t): one value per lane; wave-synchronous LDS exchange (no barrier)
        uw[sq * 4 + q] = sigmoidf_(fmaf(wh0, x0, fmaf(wh1, x1, fmaf(wh2, x2, bhc))));

        // B fragments from h(t-1): truncation hi + truncation lo
        Frag bhi[2], blo[2];
        #pragma unroll
        for (int kt = 0; kt < 2; ++kt){
            const float4 hA = *(const float4*)&hw[sq*68 + 32*kt + 8*q];
            const float4 hB = *(const float4*)&hw[sq*68 + 32*kt + 8*q + 4];
            const float f[8] = {hA.x, hA.y, hA.z, hA.w, hB.x, hB.y, hB.z, hB.w};
            #pragma unroll
            for (int p = 0; p < 4; ++p){
                const u32 hi = pack_trunc(f[2*p], f[2*p+1]);
                bhi[kt].u[p] = hi;
                const float l0 = f[2*p]   - bitsf((hi & 0xFFFFu) << 16);
                const float l1 = f[2*p+1] - bitsf(hi & 0xFFFF0000u);
                blo[kt].u[p] = pack_trunc(l0, l1);
            }
        }

        // MFMA: D = Whh·h  (split: AhiBhi + AhiBlo + AloBhi), 12 indep chains
        f32x4 acc[12];
        #pragma unroll
        for (int mt = 0; mt < 12; ++mt) acc[mt] = (f32x4){0.f, 0.f, 0.f, 0.f};
        #pragma unroll
        for (int kt = 0; kt < 2; ++kt){
            #pragma unroll
            for (int mt = 0; mt < 12; ++mt)
                acc[mt] = __builtin_amdgcn_mfma_f32_16x16x32_bf16(ahi[mt][kt].s, bhi[kt].s, acc[mt], 0, 0, 0);
            #pragma unroll
            for (int mt = 0; mt < 12; ++mt)
                acc[mt] = __builtin_amdgcn_mfma_f32_16x16x32_bf16(ahi[mt][kt].s, blo[kt].s, acc[mt], 0, 0, 0);
            #pragma unroll
            for (int mt = 0; mt < 12; ++mt)
                acc[mt] = __builtin_amdgcn_mfma_f32_16x16x32_bf16(alo[mt][kt].s, bhi[kt].s, acc[mt], 0, 0, 0);
        }

        // input gates (K=4, VALU; wih broadcast reads; independent of MFMA)
        const float4 u4 = *(const float4*)&uw[sq * 4];
        float gi[12][4];
        #pragma unroll
        for (int mt = 0; mt < 12; ++mt){
            #pragma unroll
            for (int r = 0; r < 4; ++r){
                const float4 w4 = *(const float4*)&sm.wih[(16*mt + 4*q + r) * 4];
                gi[mt][r] = fmaf(w4.x, u4.x, fmaf(w4.y, u4.y, fmaf(w4.z, u4.z,
                            fmaf(w4.w, u4.w, ginit[mt][r]))));
            }
        }

        // gates + state update + h write-back (C-layout -> [s][k] rows)
        #pragma unroll
        for (int m = 0; m < 4; ++m){
            float4 hnew;
            #pragma unroll
            for (int r = 0; r < 4; ++r){
                const float a_r = acc[m][r]     + gi[m][r];
                const float a_z = acc[m + 4][r] + gi[m + 4][r];
                const float rr = sigmoidf_(a_r);
                const float zz = sigmoidf_(a_z);
                const float a_n = fmaf(rr, acc[m + 8][r], fmaf(rr, bhhn[m][r], gi[m + 8][r]));
                const float cand = tanhf_(a_n);
                const float hn = fmaf(zz, hreg[m][r] - cand, cand);
                hreg[m][r] = hn;
                ((float*)&hnew)[r] = hn;
            }
            *(float4*)&hw[sq*68 + 16*m + 4*q] = hnew;
        }

        x0 = p0; x1 = p1; x2 = p2;
    }

    // ---- tail: per-wave, 2 b's sequentially; all LDS wave-private ----
    #pragma unroll 1
    for (int bb = 0; bb < 2; ++bb){
        const int b = b_base + bb;
        // Phase A
        {
            const int l = lane >> 3, o = lane & 7;
            float fv[8];
            const float vraw = feat[b * 16 + 8 + l];
            const int   bit  = ((int)feat[b * 16 + l]) & 1;
            #pragma unroll
            for (int c = 0; c < 4; ++c){
                fv[c]     = sigmoidf_(fmaf(vraw, Wv[c], bv[c]));
                fv[4 + c] = sigmoidf_(emb_phase[bit * 4 + c]);
            }
            const float* hrow = &hw[(bb * 8 + l) * 68];
            #pragma unroll
            for (int half = 0; half < 2; ++half){
                const int oo = o + half * 8;
                float acc = sm.bl[oo];
                #pragma unroll
                for (int f = 0; f < 8; ++f) acc = fmaf(fv[f], sm.wl[oo * 72 + f], acc);
                for (int k = 0; k < 64; ++k) acc = fmaf(hrow[k], sm.wl[oo * 72 + 8 + k], acc);
                sm.line[wave][l * 16 + oo] = fmaxf(acc, 0.0f);
            }
        }
        __builtin_amdgcn_wave_barrier();
        // Phase B
        {
            const int p = lane >> 3, o = lane & 7;
            const int l0 = (0x64204501u >> (p * 4)) & 15;
            const int l1 = (0x75316723u >> (p * 4)) & 15;
            sm.pp[wave][p * 16 + o]     = sm.line[wave][l0 * 16 + o]     + sm.line[wave][l1 * 16 + o];
            sm.pp[wave][p * 16 + o + 8] = sm.line[wave][l0 * 16 + o + 8] + sm.line[wave][l1 * 16 + o + 8];
        }
        __builtin_amdgcn_wave_barrier();
        // Phase C
        if (lane < 56){
            const int p  = lane / 7;
            const int qi = lane - p * 7;
            const int jl = qi + (qi >= p ? 1 : 0);
            float fmv[32];
            #pragma unroll
            for (int f = 0; f < 16; ++f){
                fmv[f]      = sm.pp[wave][p  * 16 + f];
                fmv[16 + f] = sm.pp[wave][jl * 16 + f];
            }
            const int rel = relation[p * 7 + qi] & 1;
            float ce[4];
            #pragma unroll
            for (int c = 0; c < 4; ++c) ce[c] = emb_const[rel * 4 + c];
            float m[20];
            for (int o = 0; o < 20; ++o){
                float xf = sm.bcf[o];
                #pragma unroll
                for (int f = 0; f < 32; ++f) xf = fmaf(fmv[f], sm.wcf[o * 32 + f], xf);
                float yc = sm.bcc[o];
                #pragma unroll
                for (int c = 0; c < 4; ++c) yc = fmaf(ce[c], sm.wcc[o * 4 + c], yc);
                m[o] = fmaxf(xf, 0.0f) * fmaxf(yc, 0.0f);
            }
            float fin = sm.bfin;
            for (int o = 0; o < 20; ++o){
                float zz = sm.bcm[o];
                #pragma unroll
                for (int c = 0; c < 20; ++c) zz = fmaf(m[c], sm.wcm[o * 20 + c], zz);
                fin = fmaf(fmaxf(zz, 0.0f), sm.wfin[o], fin);
            }
            sm.line[wave][lane] = fin;   // line dead after Phase B
        }
        __builtin_amdgcn_wave_barrier();
        if (lane < 8){
            float acc = 0.0f;
            #pragma unroll
            for (int qq = 0; qq < 7; ++qq) acc += sm.line[wave][lane * 7 + qq];
            out[b * 8 + lane] = acc;
        }
        __builtin_amdgcn_wave_barrier();   // line reused next bb
    }
}

extern "C" void kernel_launch(void* const* d_in, const int* in_sizes, int n_in,
                              void* d_out, int out_size, void* d_ws, size_t ws_size,
                              hipStream_t stream) {
    (void)n_in; (void)d_ws; (void)ws_size; (void)out_size;
    const float* feat      = (const float*)d_in[0];
    const float* hist      = (const float*)d_in[1];
    const int*   relation  = (const int*)d_in[2];
    const float* emb_phase = (const float*)d_in[3];
    const float* Wv        = (const float*)d_in[4];
    const float* bv        = (const float*)d_in[5];
    const float* Wh        = (const float*)d_in[6];
    const float* bh        = (const float*)d_in[7];
    const float* Wih       = (const float*)d_in[8];
    const float* Whh       = (const float*)d_in[9];
    const float* bih       = (const float*)d_in[10];
    const float* bhh       = (const float*)d_in[11];
    const float* Wl        = (const float*)d_in[12];
    const float* bl        = (const float*)d_in[13];
    const float* emb_const = (const float*)d_in[14];
    const float* Wcf       = (const float*)d_in[15];
    const float* bcf       = (const float*)d_in[16];
    const float* Wcc       = (const float*)d_in[17];
    const float* bcc       = (const float*)d_in[18];
    const float* Wcm       = (const float*)d_in[19];
    const float* bcm       = (const float*)d_in[20];
    const float* Wfin      = (const float*)d_in[21];
    const float* bfin      = (const float*)d_in[22];
    float* out = (float*)d_out;

    const int B = in_sizes[0] / 16;     // 2048
    const int nblocks = B / 8;          // 4 waves/block x 2 b/wave
    FRAPRQ_fused_kernel<<<nblocks, 256, 0, stream>>>(
        feat, hist, relation, emb_phase, Wv, bv, Wh, bh, Wih, Whh, bih, bhh,
        Wl, bl, emb_const, Wcf, bcf, Wcc, bcc, Wcm, bcm, Wfin, bfin, out);
}